// Round 2
// baseline (155.078 us; speedup 1.0000x reference)
//
#include <hip/hip_runtime.h>

// Problem constants (from reference)
constexpr int B_  = 2;
constexpr int T_  = 1024;
constexpr int NQ  = 32;
constexpr int NKV = 8;
constexpr int D_  = 128;

constexpr int BM = 64;   // query rows per workgroup (4 waves x 16)
constexpr int BN = 32;   // keys per KV block
constexpr float MASK_NEG = -3.0e38f;

typedef __bf16 bf16;
typedef __bf16 bf16x2 __attribute__((ext_vector_type(2)));
typedef __bf16 bf16x4 __attribute__((ext_vector_type(4)));
typedef __bf16 bf16x8 __attribute__((ext_vector_type(8)));
typedef float  floatx4 __attribute__((ext_vector_type(4)));

// Flash attention, causal + segment masking, GQA (4 q-heads per kv head).
// Precision: QK^T uses compensated bf16 split (hi+lo), since bf16-rounded
// logits alone give ~0.09 absolute error -> 0.15 output error (R1 evidence).
__global__ __launch_bounds__(256)
void fa_kernel(const float* __restrict__ Qg, const float* __restrict__ Kg,
               const float* __restrict__ Vg, const int* __restrict__ seg,
               float* __restrict__ Og) {
    __shared__ bf16 lds_kh[BN][136];    // K hi tile, padded (2-way alias = free)
    __shared__ bf16 lds_kl[BN][136];    // K lo tile
    __shared__ bf16 lds_vt[D_][40];     // V transposed [d][s]
    __shared__ bf16 lds_p[4][16][40];   // per-wave P scratch (C->A layout)

    const int tile = blockIdx.x;        // 0..15
    const int h    = blockIdx.y;        // 0..31
    const int b    = blockIdx.z;        // 0..1
    const int kv   = h >> 2;            // GQA: n = kv*4 + g
    const int t0   = tile * BM;

    const int tid  = threadIdx.x;
    const int wave = tid >> 6;
    const int lane = tid & 63;
    const int quad = lane >> 4;
    const int ln   = lane & 15;

    // ---- Q fragments (A-layout: m = lane&15, k = quad*8+j), hi+lo split
    const int qrow = t0 + wave * 16 + ln;
    const float* qptr = Qg + (((size_t)b * T_ + qrow) * NQ + h) * D_;
    bf16x8 qh[4], ql[4];
#pragma unroll
    for (int c = 0; c < 4; ++c) {
        const float* p = qptr + c * 32 + quad * 8;
        float4 f0 = *(const float4*)(p);
        float4 f1 = *(const float4*)(p + 4);
        float fv[8] = {f0.x, f0.y, f0.z, f0.w, f1.x, f1.y, f1.z, f1.w};
        bf16x8 vh, vl;
#pragma unroll
        for (int j = 0; j < 8; ++j) {
            const bf16 hi = (bf16)fv[j];
            vh[j] = hi;
            vl[j] = (bf16)(fv[j] - (float)hi);
        }
        qh[c] = vh; ql[c] = vl;
    }

    // ---- per-lane softmax state for C-layout rows (row = quad*4 + r)
    int   trow[4], segq[4];
#pragma unroll
    for (int r = 0; r < 4; ++r) {
        trow[r] = t0 + wave * 16 + quad * 4 + r;
        segq[r] = seg[b * T_ + trow[r]];
    }
    const int seg_lo = seg[b * T_ + t0];   // sorted ids -> min over tile

    float  m_i[4], l_i[4];
    floatx4 o_acc[8];
#pragma unroll
    for (int r = 0; r < 4; ++r) { m_i[r] = -1.0e30f; l_i[r] = 0.0f; }
#pragma unroll
    for (int dt = 0; dt < 8; ++dt) o_acc[dt] = floatx4{0.f, 0.f, 0.f, 0.f};

    const int nblk = t0 / BN + 2;   // causal: only s0 <= t0+63

    for (int blk = 0; blk < nblk; ++blk) {
        const int s0 = blk * BN;
        // segment skip (workgroup-uniform; ids sorted)
        if (seg[b * T_ + s0 + BN - 1] < seg_lo) continue;

        __syncthreads();   // protect LDS tiles still being read

        // ---- stage K block [BN][D] -> hi/lo bf16 tiles
        {
            const int d4 = tid & 31;    // float4 column
            const int r8 = tid >> 5;    // 0..7
#pragma unroll
            for (int i = 0; i < 4; ++i) {
                const int s = r8 + 8 * i;
                const float4 f = *(const float4*)(Kg + (((size_t)b * T_ + s0 + s) * NKV + kv) * D_ + d4 * 4);
                const float fv[4] = {f.x, f.y, f.z, f.w};
                bf16x4 wh, wl;
#pragma unroll
                for (int j = 0; j < 4; ++j) {
                    const bf16 hi = (bf16)fv[j];
                    wh[j] = hi;
                    wl[j] = (bf16)(fv[j] - (float)hi);
                }
                *(bf16x4*)&lds_kh[s][d4 * 4] = wh;
                *(bf16x4*)&lds_kl[s][d4 * 4] = wl;
            }
        }
        // ---- stage V block transposed -> lds_vt[d][s]
        {
            const int dcol = tid & 127;
            const int half = tid >> 7;  // 0..1
#pragma unroll
            for (int i = 0; i < 8; ++i) {
                const int s = (half * 8 + i) * 2;
                const float a = Vg[(((size_t)b * T_ + s0 + s    ) * NKV + kv) * D_ + dcol];
                const float c = Vg[(((size_t)b * T_ + s0 + s + 1) * NKV + kv) * D_ + dcol];
                bf16x2 w2; w2[0] = (bf16)a; w2[1] = (bf16)c;
                *(bf16x2*)&lds_vt[dcol][s] = w2;
            }
        }
        __syncthreads();

        // ---- S = Q K^T (compensated): qh*kh + ql*kh + qh*kl
        floatx4 sc[2];
#pragma unroll
        for (int nt = 0; nt < 2; ++nt) {
            floatx4 acc = floatx4{0.f, 0.f, 0.f, 0.f};
#pragma unroll
            for (int c = 0; c < 4; ++c) {
                bf16x8 kh = *(const bf16x8*)&lds_kh[nt * 16 + ln][c * 32 + quad * 8];
                bf16x8 kl = *(const bf16x8*)&lds_kl[nt * 16 + ln][c * 32 + quad * 8];
                acc = __builtin_amdgcn_mfma_f32_16x16x32_bf16(qh[c], kh, acc, 0, 0, 0);
                acc = __builtin_amdgcn_mfma_f32_16x16x32_bf16(ql[c], kh, acc, 0, 0, 0);
                acc = __builtin_amdgcn_mfma_f32_16x16x32_bf16(qh[c], kl, acc, 0, 0, 0);
            }
            sc[nt] = acc;
        }

        // ---- mask (causal AND same-segment); C-layout: col = ln, row = quad*4+r
        int segs[2];
        segs[0] = seg[b * T_ + s0 + ln];
        segs[1] = seg[b * T_ + s0 + 16 + ln];
#pragma unroll
        for (int nt = 0; nt < 2; ++nt) {
            const int s = s0 + nt * 16 + ln;
#pragma unroll
            for (int r = 0; r < 4; ++r) {
                const bool ok = (s <= trow[r]) && (segs[nt] == segq[r]);
                sc[nt][r] = ok ? sc[nt][r] : MASK_NEG;
            }
        }

        // ---- online softmax (per row; redundant across 16 lanes of a quad)
        float pr[2][4];
#pragma unroll
        for (int r = 0; r < 4; ++r) {
            float mx = fmaxf(sc[0][r], sc[1][r]);
            mx = fmaxf(mx, __shfl_xor(mx, 1));
            mx = fmaxf(mx, __shfl_xor(mx, 2));
            mx = fmaxf(mx, __shfl_xor(mx, 4));
            mx = fmaxf(mx, __shfl_xor(mx, 8));
            const float mnew  = fmaxf(m_i[r], mx);
            const float alpha = __expf(m_i[r] - mnew);
            m_i[r] = mnew;
            const float p0 = __expf(sc[0][r] - mnew);
            const float p1 = __expf(sc[1][r] - mnew);
            pr[0][r] = p0; pr[1][r] = p1;
            float sm = p0 + p1;
            sm += __shfl_xor(sm, 1);
            sm += __shfl_xor(sm, 2);
            sm += __shfl_xor(sm, 4);
            sm += __shfl_xor(sm, 8);
            l_i[r] = l_i[r] * alpha + sm;
#pragma unroll
            for (int dt = 0; dt < 8; ++dt) o_acc[dt][r] *= alpha;
        }

        // ---- P: C-layout regs -> per-wave LDS -> A-layout frag
#pragma unroll
        for (int nt = 0; nt < 2; ++nt)
#pragma unroll
            for (int r = 0; r < 4; ++r)
                lds_p[wave][quad * 4 + r][nt * 16 + ln] = (bf16)pr[nt][r];

        __threadfence_block();

        // ---- O += P V : A = P[m=ln][s=quad*8+j], B = V^T[d=dt*16+ln][s=quad*8+j]
        bf16x8 afrag = *(const bf16x8*)&lds_p[wave][ln][quad * 8];
#pragma unroll
        for (int dt = 0; dt < 8; ++dt) {
            bf16x8 bfrag = *(const bf16x8*)&lds_vt[dt * 16 + ln][quad * 8];
            o_acc[dt] = __builtin_amdgcn_mfma_f32_16x16x32_bf16(afrag, bfrag, o_acc[dt], 0, 0, 0);
        }
    }

    // ---- epilogue: normalize and store (fp32 out, C-layout scatter)
#pragma unroll
    for (int r = 0; r < 4; ++r) {
        const float inv = 1.0f / l_i[r];
        float* optr = Og + (((size_t)b * T_ + trow[r]) * NQ + h) * D_ + ln;
#pragma unroll
        for (int dt = 0; dt < 8; ++dt)
            optr[dt * 16] = o_acc[dt][r] * inv;
    }
}

extern "C" void kernel_launch(void* const* d_in, const int* in_sizes, int n_in,
                              void* d_out, int out_size, void* d_ws, size_t ws_size,
                              hipStream_t stream) {
    const float* Q   = (const float*)d_in[0];
    const float* K   = (const float*)d_in[1];
    const float* V   = (const float*)d_in[2];
    const int*   seg = (const int*)d_in[3];
    float* out = (float*)d_out;
    dim3 grid(T_ / BM, NQ, B_);
    fa_kernel<<<grid, 256, 0, stream>>>(Q, K, V, seg, out);
}

// Round 3
// 141.375 us; speedup vs baseline: 1.0969x; 1.0969x over previous
//
#include <hip/hip_runtime.h>

// Problem constants (from reference)
constexpr int B_  = 2;
constexpr int T_  = 1024;
constexpr int NQ  = 32;
constexpr int NKV = 8;
constexpr int D_  = 128;

constexpr int BM = 64;            // query rows per workgroup (4 waves x 16)
constexpr int BN = 32;            // keys per KV block
constexpr int NTILE = T_ / BM;    // 16
constexpr float MASK_NEG = -3.0e38f;

typedef _Float16 f16;
typedef f16 f16x2 __attribute__((ext_vector_type(2)));
typedef f16 f16x4 __attribute__((ext_vector_type(4)));
typedef f16 f16x8 __attribute__((ext_vector_type(8)));
typedef float floatx4 __attribute__((ext_vector_type(4)));

// Flash attention, causal + segment mask, GQA. fp16 MFMA single-pass
// (fp16's 10 mantissa bits give ~6e-3 logit error vs bf16's 0.09 -> no
// compensation needed; R2's compensated-bf16 passed at 0.031, fp16 lands
// similar with 1/3 the QK MFMAs).
// Load balance: workgroup processes q-tiles {15-p, p} -> uniform 36 KV-iters.
// Prefetch: segment skip is a monotone prefix (sorted ids) -> binary-search
// blk_start once, then skip-free loop with K/V global->reg prefetch.
__global__ __launch_bounds__(256)
void fa_kernel(const float* __restrict__ Qg, const float* __restrict__ Kg,
               const float* __restrict__ Vg, const int* __restrict__ seg,
               float* __restrict__ Og) {
    __shared__ f16 lds_k[BN][136];     // K tile [s][d], padded
    __shared__ f16 lds_vt[D_][40];     // V transposed [d][s], padded
    __shared__ f16 lds_p[4][16][40];   // per-wave P scratch (C->A layout)

    const int pair = blockIdx.x;        // 0..7
    const int h    = blockIdx.y;        // 0..31
    const int b    = blockIdx.z;        // 0..1
    const int kv   = h >> 2;

    const int tid  = threadIdx.x;
    const int wave = tid >> 6;
    const int lane = tid & 63;
    const int quad = lane >> 4;
    const int ln   = lane & 15;

    // staging ownership
    const int kd4 = tid & 31, kr8 = tid >> 5;     // K: float4 col, row group
    const int vd  = tid & 127, vhalf = tid >> 7;  // V: d column, s half

    const int* segb = seg + b * T_;

    for (int sub = 0; sub < 2; ++sub) {
        const int tile = (sub == 0) ? (NTILE - 1 - pair) : pair;  // heavy first
        const int t0 = tile * BM;

        // ---- Q fragments (A-layout: m = ln, k = quad*8+j)
        const int qrow = t0 + wave * 16 + ln;
        const float* qptr = Qg + (((size_t)b * T_ + qrow) * NQ + h) * D_;
        f16x8 qfrag[4];
#pragma unroll
        for (int c = 0; c < 4; ++c) {
            const float* p = qptr + c * 32 + quad * 8;
            float4 f0 = *(const float4*)(p);
            float4 f1 = *(const float4*)(p + 4);
            f16x8 v;
            v[0] = (f16)f0.x; v[1] = (f16)f0.y; v[2] = (f16)f0.z; v[3] = (f16)f0.w;
            v[4] = (f16)f1.x; v[5] = (f16)f1.y; v[6] = (f16)f1.z; v[7] = (f16)f1.w;
            qfrag[c] = v;
        }

        int trow[4], segq[4];
#pragma unroll
        for (int r = 0; r < 4; ++r) {
            trow[r] = t0 + wave * 16 + quad * 4 + r;
            segq[r] = segb[trow[r]];
        }
        const int seg_lo = segb[t0];

        // first KV block with any key in an active segment:
        // lower_bound(seg, seg_lo) >> 5  (ids sorted ascending)
        int lo = 0, hi = t0;
        while (lo < hi) {
            const int mid = (lo + hi) >> 1;
            if (segb[mid] < seg_lo) lo = mid + 1; else hi = mid;
        }
        const int blk_start = lo >> 5;
        const int nblk = 2 * tile + 2;   // causal limit

        float  m_i[4], l_i[4];
        floatx4 o_acc[8];
#pragma unroll
        for (int r = 0; r < 4; ++r) { m_i[r] = -1.0e30f; l_i[r] = 0.0f; }
#pragma unroll
        for (int dt = 0; dt < 8; ++dt) o_acc[dt] = floatx4{0.f, 0.f, 0.f, 0.f};

        // ---- prefetch first KV block into registers
        float4 kreg[4];
        float  vreg[16];
        {
            const int s0 = blk_start * BN;
            const float* kb = Kg + (((size_t)b * T_ + s0 + kr8) * NKV + kv) * D_ + kd4 * 4;
#pragma unroll
            for (int i = 0; i < 4; ++i)
                kreg[i] = *(const float4*)(kb + (size_t)(8 * i) * NKV * D_);
            const float* vb = Vg + (((size_t)b * T_ + s0 + vhalf * 16) * NKV + kv) * D_ + vd;
#pragma unroll
            for (int i = 0; i < 16; ++i)
                vreg[i] = vb[(size_t)i * NKV * D_];
        }

        for (int blk = blk_start; blk < nblk; ++blk) {
            const int s0 = blk * BN;
            __syncthreads();   // previous compute done -> LDS reusable

            // ---- convert prefetched regs -> LDS tiles
#pragma unroll
            for (int i = 0; i < 4; ++i) {
                f16x4 w;
                w[0] = (f16)kreg[i].x; w[1] = (f16)kreg[i].y;
                w[2] = (f16)kreg[i].z; w[3] = (f16)kreg[i].w;
                *(f16x4*)&lds_k[kr8 + 8 * i][kd4 * 4] = w;
            }
#pragma unroll
            for (int i = 0; i < 8; ++i) {
                f16x2 w; w[0] = (f16)vreg[2 * i]; w[1] = (f16)vreg[2 * i + 1];
                *(f16x2*)&lds_vt[vd][vhalf * 16 + 2 * i] = w;
            }

            // ---- prefetch next KV block (drains during compute)
            if (blk + 1 < nblk) {
                const int s0n = s0 + BN;
                const float* kb = Kg + (((size_t)b * T_ + s0n + kr8) * NKV + kv) * D_ + kd4 * 4;
#pragma unroll
                for (int i = 0; i < 4; ++i)
                    kreg[i] = *(const float4*)(kb + (size_t)(8 * i) * NKV * D_);
                const float* vb = Vg + (((size_t)b * T_ + s0n + vhalf * 16) * NKV + kv) * D_ + vd;
#pragma unroll
                for (int i = 0; i < 16; ++i)
                    vreg[i] = vb[(size_t)i * NKV * D_];
            }
            __syncthreads();

            // ---- S = Q K^T (fp16, single pass)
            floatx4 sc[2];
#pragma unroll
            for (int nt = 0; nt < 2; ++nt) {
                floatx4 acc = floatx4{0.f, 0.f, 0.f, 0.f};
#pragma unroll
                for (int c = 0; c < 4; ++c) {
                    f16x8 kf = *(const f16x8*)&lds_k[nt * 16 + ln][c * 32 + quad * 8];
                    acc = __builtin_amdgcn_mfma_f32_16x16x32_f16(qfrag[c], kf, acc, 0, 0, 0);
                }
                sc[nt] = acc;
            }

            // ---- mask (causal AND segment); C-layout: col=ln, row=quad*4+r
            int segs[2];
            segs[0] = segb[s0 + ln];
            segs[1] = segb[s0 + 16 + ln];
#pragma unroll
            for (int nt = 0; nt < 2; ++nt) {
                const int s = s0 + nt * 16 + ln;
#pragma unroll
                for (int r = 0; r < 4; ++r) {
                    const bool ok = (s <= trow[r]) && (segs[nt] == segq[r]);
                    sc[nt][r] = ok ? sc[nt][r] : MASK_NEG;
                }
            }

            // ---- online softmax
            float pr[2][4];
#pragma unroll
            for (int r = 0; r < 4; ++r) {
                float mx = fmaxf(sc[0][r], sc[1][r]);
                mx = fmaxf(mx, __shfl_xor(mx, 1));
                mx = fmaxf(mx, __shfl_xor(mx, 2));
                mx = fmaxf(mx, __shfl_xor(mx, 4));
                mx = fmaxf(mx, __shfl_xor(mx, 8));
                const float mnew  = fmaxf(m_i[r], mx);
                const float alpha = __expf(m_i[r] - mnew);
                m_i[r] = mnew;
                const float p0 = __expf(sc[0][r] - mnew);
                const float p1 = __expf(sc[1][r] - mnew);
                pr[0][r] = p0; pr[1][r] = p1;
                float sm = p0 + p1;
                sm += __shfl_xor(sm, 1);
                sm += __shfl_xor(sm, 2);
                sm += __shfl_xor(sm, 4);
                sm += __shfl_xor(sm, 8);
                l_i[r] = l_i[r] * alpha + sm;
#pragma unroll
                for (int dt = 0; dt < 8; ++dt) o_acc[dt][r] *= alpha;
            }

            // ---- P: C-layout regs -> per-wave LDS -> A-layout frag
#pragma unroll
            for (int nt = 0; nt < 2; ++nt)
#pragma unroll
                for (int r = 0; r < 4; ++r)
                    lds_p[wave][quad * 4 + r][nt * 16 + ln] = (f16)pr[nt][r];

            __threadfence_block();   // lgkmcnt(0): same-wave LDS RAW

            // ---- O += P V
            f16x8 afrag = *(const f16x8*)&lds_p[wave][ln][quad * 8];
#pragma unroll
            for (int dt = 0; dt < 8; ++dt) {
                f16x8 bfrag = *(const f16x8*)&lds_vt[dt * 16 + ln][quad * 8];
                o_acc[dt] = __builtin_amdgcn_mfma_f32_16x16x32_f16(afrag, bfrag, o_acc[dt], 0, 0, 0);
            }
        }

        // ---- epilogue: normalize + store this sub-tile
#pragma unroll
        for (int r = 0; r < 4; ++r) {
            const float inv = 1.0f / l_i[r];
            float* optr = Og + (((size_t)b * T_ + trow[r]) * NQ + h) * D_ + ln;
#pragma unroll
            for (int dt = 0; dt < 8; ++dt)
                optr[dt * 16] = o_acc[dt][r] * inv;
        }
    }
}

extern "C" void kernel_launch(void* const* d_in, const int* in_sizes, int n_in,
                              void* d_out, int out_size, void* d_ws, size_t ws_size,
                              hipStream_t stream) {
    const float* Q   = (const float*)d_in[0];
    const float* K   = (const float*)d_in[1];
    const float* V   = (const float*)d_in[2];
    const int*   seg = (const int*)d_in[3];
    float* out = (float*)d_out;
    dim3 grid(NTILE / 2, NQ, B_);
    fa_kernel<<<grid, 256, 0, stream>>>(Q, K, V, seg, out);
}

// Round 4
// 130.957 us; speedup vs baseline: 1.1842x; 1.0795x over previous
//
#include <hip/hip_runtime.h>

// Problem constants (from reference)
constexpr int B_  = 2;
constexpr int T_  = 1024;
constexpr int NQ  = 32;
constexpr int NKV = 8;
constexpr int D_  = 128;

constexpr int BM = 64;            // query rows per workgroup (4 waves x 16)
constexpr int BN = 64;            // keys per KV iteration
constexpr int NTILE = T_ / BM;    // 16
constexpr float MASK_NEG = -3.0e38f;

typedef _Float16 f16;
typedef f16 f16x2 __attribute__((ext_vector_type(2)));
typedef f16 f16x4 __attribute__((ext_vector_type(4)));
typedef f16 f16x8 __attribute__((ext_vector_type(8)));
typedef float floatx4 __attribute__((ext_vector_type(4)));

// Flash attention, causal + segment mask, GQA, fp16 MFMA.
// R4 structure: prefetch is issued AFTER the post-staging barrier (so the
// global loads stay in flight across the whole compute phase -- R3 issued
// them before the barrier, whose implicit s_waitcnt vmcnt(0) drained them),
// and the P round-trip uses an lgkmcnt-only wait instead of
// __threadfence_block (which drains vmcnt(0) mid-compute).
__global__ __launch_bounds__(256)
void fa_kernel(const float* __restrict__ Qg, const float* __restrict__ Kg,
               const float* __restrict__ Vg, const int* __restrict__ seg,
               float* __restrict__ Og) {
    __shared__ f16 lds_k[BN][136];     // K tile [s][d], pad 128->136 (16B-aligned rows)
    __shared__ f16 lds_vt[D_][72];     // V transposed [d][s], pad 64->72
    __shared__ f16 lds_p[4][16][72];   // per-wave P scratch (C->A layout)
    __shared__ int lds_seg[T_];        // segment ids for this batch row

    const int pair = blockIdx.x;        // 0..7
    const int h    = blockIdx.y;        // 0..31
    const int b    = blockIdx.z;        // 0..1
    const int kv   = h >> 2;

    const int tid  = threadIdx.x;
    const int wave = tid >> 6;
    const int lane = tid & 63;
    const int quad = lane >> 4;
    const int ln   = lane & 15;

    // staging ownership
    const int kd4 = tid & 31, kr8 = tid >> 5;     // K: float4 col, row base (8 rows, stride 8)
    const int vd  = tid & 127, vhalf = tid >> 7;  // V: d column, 32-row half

    const int* segb = seg + b * T_;
    *(int4*)&lds_seg[tid * 4] = *(const int4*)(segb + tid * 4);
    __syncthreads();

    for (int sub = 0; sub < 2; ++sub) {
        const int tile = sub ? pair : (NTILE - 1 - pair);  // heavy tile first
        const int t0 = tile * BM;

        // ---- Q fragments (A-layout: m = ln, k = quad*8+j)
        const int qrow = t0 + wave * 16 + ln;
        const float* qptr = Qg + (((size_t)b * T_ + qrow) * NQ + h) * D_;
        f16x8 qfrag[4];
#pragma unroll
        for (int c = 0; c < 4; ++c) {
            const float* p = qptr + c * 32 + quad * 8;
            float4 f0 = *(const float4*)(p);
            float4 f1 = *(const float4*)(p + 4);
            f16x8 v;
            v[0] = (f16)f0.x; v[1] = (f16)f0.y; v[2] = (f16)f0.z; v[3] = (f16)f0.w;
            v[4] = (f16)f1.x; v[5] = (f16)f1.y; v[6] = (f16)f1.z; v[7] = (f16)f1.w;
            qfrag[c] = v;
        }

        int trow[4], segq[4];
#pragma unroll
        for (int r = 0; r < 4; ++r) {
            trow[r] = t0 + wave * 16 + quad * 4 + r;
            segq[r] = lds_seg[trow[r]];
        }
        const int seg_lo = lds_seg[t0];

        // first active KV block: count fully-dead 16-chunks via ballot (ids sorted)
        unsigned long long bal = __ballot(lds_seg[lane * 16 + 15] < seg_lo);
        const int blk_start = __popcll(bal) >> 2;   // 16-chunks -> 64-chunks, round down
        const int nblk = tile + 1;                  // causal limit (keys < (tile+1)*64)

        float  m_i[4], l_i[4];
        floatx4 o_acc[8];
#pragma unroll
        for (int r = 0; r < 4; ++r) { m_i[r] = -1.0e30f; l_i[r] = 0.0f; }
#pragma unroll
        for (int dt = 0; dt < 8; ++dt) o_acc[dt] = floatx4{0.f, 0.f, 0.f, 0.f};

        // ---- prologue: load first KV block into registers
        float4 kreg[8];
        float  vreg[32];
        {
            const int s0 = blk_start * BN;
            const float* kb = Kg + (((size_t)b * T_ + s0 + kr8) * NKV + kv) * D_ + kd4 * 4;
#pragma unroll
            for (int i = 0; i < 8; ++i)
                kreg[i] = *(const float4*)(kb + (size_t)(8 * i) * NKV * D_);
            const float* vb = Vg + (((size_t)b * T_ + s0 + vhalf * 32) * NKV + kv) * D_ + vd;
#pragma unroll
            for (int i = 0; i < 32; ++i)
                vreg[i] = vb[(size_t)i * NKV * D_];
        }

        for (int blk = blk_start; blk < nblk; ++blk) {
            const int s0 = blk * BN;
            __syncthreads();   // [A] all waves done with previous LDS contents
                               //     (its vmcnt(0) also lands the prefetch we need NOW)

            // ---- regs -> LDS tiles (fp32 -> fp16)
#pragma unroll
            for (int i = 0; i < 8; ++i) {
                f16x4 w;
                w[0] = (f16)kreg[i].x; w[1] = (f16)kreg[i].y;
                w[2] = (f16)kreg[i].z; w[3] = (f16)kreg[i].w;
                *(f16x4*)&lds_k[kr8 + 8 * i][kd4 * 4] = w;
            }
#pragma unroll
            for (int i = 0; i < 16; ++i) {
                f16x2 w; w[0] = (f16)vreg[2 * i]; w[1] = (f16)vreg[2 * i + 1];
                *(f16x2*)&lds_vt[vd][vhalf * 32 + 2 * i] = w;
            }
            __syncthreads();   // [B] tiles visible; nothing outstanding to drain

            // ---- prefetch next block AFTER the barrier: stays in flight
            if (blk + 1 < nblk) {
                const int s0n = s0 + BN;
                const float* kb = Kg + (((size_t)b * T_ + s0n + kr8) * NKV + kv) * D_ + kd4 * 4;
#pragma unroll
                for (int i = 0; i < 8; ++i)
                    kreg[i] = *(const float4*)(kb + (size_t)(8 * i) * NKV * D_);
                const float* vb = Vg + (((size_t)b * T_ + s0n + vhalf * 32) * NKV + kv) * D_ + vd;
#pragma unroll
                for (int i = 0; i < 32; ++i)
                    vreg[i] = vb[(size_t)i * NKV * D_];
            }

            // ---- S = Q K^T over 4 n-tiles of 16 keys
            floatx4 sc[4];
#pragma unroll
            for (int nt = 0; nt < 4; ++nt) {
                floatx4 acc = floatx4{0.f, 0.f, 0.f, 0.f};
#pragma unroll
                for (int c = 0; c < 4; ++c) {
                    f16x8 kf = *(const f16x8*)&lds_k[nt * 16 + ln][c * 32 + quad * 8];
                    acc = __builtin_amdgcn_mfma_f32_16x16x32_f16(qfrag[c], kf, acc, 0, 0, 0);
                }
                sc[nt] = acc;
            }

            // ---- mask (causal AND segment); C-layout: col=ln, row=quad*4+r
#pragma unroll
            for (int nt = 0; nt < 4; ++nt) {
                const int s = s0 + nt * 16 + ln;
                const int sgs = lds_seg[s];
#pragma unroll
                for (int r = 0; r < 4; ++r) {
                    const bool ok = (s <= trow[r]) && (sgs == segq[r]);
                    sc[nt][r] = ok ? sc[nt][r] : MASK_NEG;
                }
            }

            // ---- online softmax (one chain per row over 64 keys)
#pragma unroll
            for (int r = 0; r < 4; ++r) {
                float mx = fmaxf(fmaxf(sc[0][r], sc[1][r]), fmaxf(sc[2][r], sc[3][r]));
                mx = fmaxf(mx, __shfl_xor(mx, 1));
                mx = fmaxf(mx, __shfl_xor(mx, 2));
                mx = fmaxf(mx, __shfl_xor(mx, 4));
                mx = fmaxf(mx, __shfl_xor(mx, 8));
                const float mnew  = fmaxf(m_i[r], mx);
                const float alpha = __expf(m_i[r] - mnew);
                m_i[r] = mnew;
                float p0 = __expf(sc[0][r] - mnew);
                float p1 = __expf(sc[1][r] - mnew);
                float p2 = __expf(sc[2][r] - mnew);
                float p3 = __expf(sc[3][r] - mnew);
                sc[0][r] = p0; sc[1][r] = p1; sc[2][r] = p2; sc[3][r] = p3;
                float sm = (p0 + p1) + (p2 + p3);
                sm += __shfl_xor(sm, 1);
                sm += __shfl_xor(sm, 2);
                sm += __shfl_xor(sm, 4);
                sm += __shfl_xor(sm, 8);
                l_i[r] = l_i[r] * alpha + sm;
#pragma unroll
                for (int dt = 0; dt < 8; ++dt) o_acc[dt][r] *= alpha;
            }

            // ---- P: C-layout regs -> per-wave LDS -> A-layout frags
#pragma unroll
            for (int nt = 0; nt < 4; ++nt)
#pragma unroll
                for (int r = 0; r < 4; ++r)
                    lds_p[wave][quad * 4 + r][nt * 16 + ln] = (f16)sc[nt][r];

            __builtin_amdgcn_s_waitcnt(0xc07f);   // lgkmcnt(0) only — no vmem drain

            f16x8 af0 = *(const f16x8*)&lds_p[wave][ln][quad * 8];
            f16x8 af1 = *(const f16x8*)&lds_p[wave][ln][32 + quad * 8];

            // ---- O += P V (K-dim 64 = 2 chained MFMAs per d-tile)
#pragma unroll
            for (int dt = 0; dt < 8; ++dt) {
                f16x8 b0 = *(const f16x8*)&lds_vt[dt * 16 + ln][quad * 8];
                f16x8 b1 = *(const f16x8*)&lds_vt[dt * 16 + ln][32 + quad * 8];
                o_acc[dt] = __builtin_amdgcn_mfma_f32_16x16x32_f16(af0, b0, o_acc[dt], 0, 0, 0);
                o_acc[dt] = __builtin_amdgcn_mfma_f32_16x16x32_f16(af1, b1, o_acc[dt], 0, 0, 0);
            }
        }

        // ---- epilogue: normalize + store this sub-tile (fp32, C-layout scatter)
#pragma unroll
        for (int r = 0; r < 4; ++r) {
            const float inv = 1.0f / l_i[r];
            float* optr = Og + (((size_t)b * T_ + trow[r]) * NQ + h) * D_ + ln;
#pragma unroll
            for (int dt = 0; dt < 8; ++dt)
                optr[dt * 16] = o_acc[dt][r] * inv;
        }
    }
}

extern "C" void kernel_launch(void* const* d_in, const int* in_sizes, int n_in,
                              void* d_out, int out_size, void* d_ws, size_t ws_size,
                              hipStream_t stream) {
    const float* Q   = (const float*)d_in[0];
    const float* K   = (const float*)d_in[1];
    const float* V   = (const float*)d_in[2];
    const int*   seg = (const int*)d_in[3];
    float* out = (float*)d_out;
    dim3 grid(NTILE / 2, NQ, B_);
    fa_kernel<<<grid, 256, 0, stream>>>(Q, K, V, seg, out);
}